// Round 8
// baseline (163.504 us; speedup 1.0000x reference)
//
#include <hip/hip_runtime.h>
#include <hip/hip_bf16.h>
#include <hip/hip_fp16.h>

#define BS 8
#define C  256
#define N  9216
#define E  9215
#define MAXD 128               // off[] bins; actual depth <= 64 (6 doubling iters)
#define LVL_STRIDE 192         // per-batch ints: [0..128]=off, 129=maxd, 130=loE, 131=hiS
#define NARROW 128             // R8: 64->128, more levels on the fence-only path
#define WT 63                  // weight tasks per batch: 4 x 5ch + 59 x 4ch = 256
#define NBLK (BS + BS * WT)    // 8 levels + 504 weights = 512 blocks = 2/CU
                               // setup LDS = 79.4 KB < 80 KB -> 2 blocks/CU co-resident

typedef __attribute__((address_space(1))) const void GVoid;
typedef __attribute__((address_space(3))) void LVoid;

// ---------------------------------------------------------------------------
// Kernel 1 (R8): 2 blocks/CU. Weight task = 4-5 channels (was 9): the two
// co-resident blocks hide each other's stage->gather serial latency, and the
// per-block critical path drops 9 -> 5 channels. LDS 79.4 KB (fits 2/CU,
// 32 waves/CU). launch_bounds(1024,8) caps VGPR<=64 (roles measured ~52).
// ---------------------------------------------------------------------------
__global__ __launch_bounds__(1024, 8) void setup_kernel(const float* __restrict__ emb,
                                                        const int* __restrict__ tree,
                                                        float* __restrict__ distG,
                                                        int* __restrict__ uparr,
                                                        int* __restrict__ lvlOff) {
    __shared__ int P[N];
    __shared__ int U[N];
    __shared__ int cnt8[MAXD * 8];
    __shared__ int tot[MAXD];
    __shared__ int sc1[MAXD];
    __shared__ int off[MAXD + 1];
    __shared__ int maxd_sh;
    const int tid = threadIdx.x;

    if (blockIdx.x >= BS) {
        // ---- weights role ----
        const int wb = blockIdx.x - BS;        // [0,504)
        const int b  = wb & 7;                 // batch fastest -> spreads XCD traffic
        const int g  = wb >> 3;                // [0,63)
        const int c0  = (g < 4) ? g * 5 : 20 + (g - 4) * 4;
        const int cpg = (g < 4) ? 5 : 4;
        const int wave = tid >> 6, lane = tid & 63;

        float* cur = (float*)P;
        float* nxt = (float*)U;

        int se[9];
        #pragma unroll
        for (int k = 0; k < 9; ++k) {
            int e = tid + k * 1024;
            se[k] = (e < E) ? tree[((size_t)b * E + e) * 2] : 0;
        }
        float acc[9];
        #pragma unroll
        for (int k = 0; k < 9; ++k) acc[k] = 0.f;

        const float* rowbase = emb + ((size_t)b * C + c0) * N;
        for (int chk = wave; chk < 36; chk += 16)
            __builtin_amdgcn_global_load_lds(
                (GVoid*)(rowbase + chk * 256 + lane * 4),
                (LVoid*)(cur + chk * 256), 16, 0, 0);
        __syncthreads();

        for (int cc = 0; cc < cpg; ++cc) {
            if (cc + 1 < cpg) {
                const float* src = rowbase + (size_t)(cc + 1) * N;
                for (int chk = wave; chk < 36; chk += 16)
                    __builtin_amdgcn_global_load_lds(
                        (GVoid*)(src + chk * 256 + lane * 4),
                        (LVoid*)(nxt + chk * 256), 16, 0, 0);
            }
            #pragma unroll
            for (int k = 0; k < 9; ++k) {
                int e = tid + k * 1024;
                if (e < E) {
                    float d = cur[se[k]] - cur[e + 1];   // tgt = e+1 (children=arange)
                    acc[k] += d * d;
                }
            }
            __syncthreads();
            float* t = cur; cur = nxt; nxt = t;
        }
        #pragma unroll
        for (int k = 0; k < 9; ++k) {
            int e = tid + k * 1024;
            if (e < E) atomicAdd(&distG[(size_t)b * N + e], acc[k]);
        }
        return;
    }

    // ---- levels role (unchanged, proven) ----
    const int b = blockIdx.x;
    const int* tb = tree + b * E * 2;

    for (int t = tid; t < N; t += 1024)
        P[t] = (t == 0) ? 0 : (tb[(t - 1) * 2] | (1 << 16));
    for (int i = tid; i < MAXD * 8; i += 1024) cnt8[i] = 0;
    if (tid == 0) maxd_sh = 1;
    __syncthreads();

    for (int r = 0; r < 3; ++r) {
        for (int t = tid; t < N; t += 1024) {
            int p = P[t];
            int a = p & 0xffff;
            if (a == 0) U[t] = p;
            else {
                int pa = P[a];
                U[t] = (pa & 0xffff) | (((p >> 16) + (pa >> 16)) << 16);
            }
        }
        __syncthreads();
        for (int t = tid; t < N; t += 1024) {
            int p = U[t];
            int a = p & 0xffff;
            if (a == 0) P[t] = p;
            else {
                int pa = U[a];
                P[t] = (pa & 0xffff) | (((p >> 16) + (pa >> 16)) << 16);
            }
        }
        __syncthreads();
    }

    for (int t = 1 + tid; t < N; t += 1024) {
        int d = P[t] >> 16;
        atomicAdd(&cnt8[d * 8 + (tid >> 7)], 1);
    }
    __syncthreads();

    for (int d = tid; d < MAXD; d += 1024) {
        int s = 0;
        #pragma unroll
        for (int k = 0; k < 8; ++k) {
            int v = cnt8[d * 8 + k];
            cnt8[d * 8 + k] = s;
            s += v;
        }
        tot[d] = s;
        if (s > 0) atomicMax(&maxd_sh, d);
    }
    __syncthreads();

    {
        int* src = tot; int* dst = sc1;
        for (int step = 1; step < MAXD; step <<= 1) {
            for (int d = tid; d < MAXD; d += 1024)
                dst[d] = src[d] + ((d >= step) ? src[d - step] : 0);
            __syncthreads();
            int* tmp = src; src = dst; dst = tmp;
        }
        for (int d = tid; d < MAXD; d += 1024) off[d + 1] = src[d];
        if (tid == 0) off[0] = 0;
    }
    __syncthreads();

    if (tid == 0) {
        int md = maxd_sh;
        int lo = 0;
        while (lo < md && off[lo + 2] - off[lo + 1] <= NARROW) ++lo;
        int hi = md + 1;
        while (hi > lo + 1 && off[hi] - off[hi - 1] <= NARROW) --hi;
        lvlOff[b * LVL_STRIDE + 129] = md;
        lvlOff[b * LVL_STRIDE + 130] = lo;
        lvlOff[b * LVL_STRIDE + 131] = hi;
    }
    for (int t = 1 + tid; t < N; t += 1024) {
        int d = P[t] >> 16;
        int idx = atomicAdd(&cnt8[d * 8 + (tid >> 7)], 1);
        int slot = off[d] + idx;
        int p = tb[(t - 1) * 2];
        U[slot] = t | (p << 16);
    }
    __syncthreads();

    for (int i = tid; i < E; i += 1024) uparr[b * N + i] = U[i];
    for (int i = tid; i <= MAXD; i += 1024) lvlOff[b * LVL_STRIDE + i] = off[i];
}

// ---------------------------------------------------------------------------
// Kernel 2: R7's proven structure (1024 threads, LDS-staged init). NARROW=128
// widens the fence-only sections via setup's loE/hiS (dp code unchanged).
// ---------------------------------------------------------------------------
__device__ __forceinline__ void up_edge(float2* V, const int2& ew) {
    int t = ew.x & 0xffff, p = ew.x >> 16;
    float w = __int_as_float(ew.y);
    float2 vt = V[t];
    atomicAdd(&V[p].x, w * vt.x);
    atomicAdd(&V[p].y, w * vt.y);
}

__device__ __forceinline__ void down_edge(float2* V, const int2& ew) {
    int t = ew.x & 0xffff, s = ew.x >> 16;
    float w = __int_as_float(ew.y);
    float2 vs = V[s], vt = V[t];
    float c = 1.f - w * w;
    V[t] = make_float2(w * vs.x + c * vt.x, w * vs.y + c * vt.y);
}

__global__ __launch_bounds__(1024) void dp_kernel(const float* __restrict__ feat,
                                                  const int* __restrict__ lvlOff,
                                                  const int* __restrict__ uparr,
                                                  const float* __restrict__ distG,
                                                  float* __restrict__ out) {
    const int b = blockIdx.x;
    const int tid = threadIdx.x;
    __shared__ float2 V[N];           // scratch: dist stage; then (F, G)
    __shared__ int2 TSW[N];           // (child|parent<<16, w bits), level order
    __shared__ int off[MAXD + 1];
    __shared__ int meta[3];           // maxd, loE, hiS

    for (int i = tid; i <= MAXD; i += 1024) off[i] = lvlOff[b * LVL_STRIDE + i];
    if (tid < 3) meta[tid] = lvlOff[b * LVL_STRIDE + 129 + tid];

    // stage dist coalesced into V-scratch (36 KB)
    float* dScr = (float*)V;
    const float* dG = distG + b * N;
    for (int i = tid; i < N; i += 1024) dScr[i] = dG[i];
    __syncthreads();

    // TSW fill: coalesced ts + LDS gather + exp (no global dependent chain)
    const int* uA = uparr + b * N;
    for (int i = tid; i < E; i += 1024) {
        int ts = uA[i];
        float ds = dScr[(ts & 0xffff) - 1];
        TSW[i] = make_int2(ts, __float_as_int(__expf(-0.01f * ds)));
    }
    __syncthreads();

    // V init (overwrites scratch)
    for (int i = tid; i < N; i += 1024)
        V[i] = make_float2(feat[b * N + i], 1.0f);
    __syncthreads();
    const int maxd = meta[0], loE = meta[1], hiS = meta[2];

    // ---- up pass (deepest level first) ----
    if (tid < 64) {                                  // narrow deep tail: wave 0
        for (int lev = maxd; lev >= hiS; --lev) {
            int s0 = off[lev], s1 = off[lev + 1];
            for (int i = s0 + tid; i < s1; i += 64) up_edge(V, TSW[i]);
            __threadfence_block();
        }
    }
    __syncthreads();
    for (int lev = hiS - 1; lev > loE; --lev) {      // wide middle: 8 waves
        int s0 = off[lev], s1 = off[lev + 1];
        if (tid < 512) {
            for (int i = s0 + tid; i < s1; i += 512) up_edge(V, TSW[i]);
        }
        __syncthreads();
    }
    if (tid < 64) {                                  // narrow top: wave 0
        for (int lev = loE; lev >= 1; --lev) {
            int s0 = off[lev], s1 = off[lev + 1];
            for (int i = s0 + tid; i < s1; i += 64) up_edge(V, TSW[i]);
            __threadfence_block();
        }
    }
    __syncthreads();

    // ---- down pass (root to leaf) ----
    if (tid < 64) {                                  // narrow top: wave 0
        for (int lev = 1; lev <= loE; ++lev) {
            int s0 = off[lev], s1 = off[lev + 1];
            for (int i = s0 + tid; i < s1; i += 64) down_edge(V, TSW[i]);
            __threadfence_block();
        }
    }
    __syncthreads();
    for (int lev = loE + 1; lev < hiS; ++lev) {      // wide middle: 8 waves
        int s0 = off[lev], s1 = off[lev + 1];
        if (tid < 512) {
            for (int i = s0 + tid; i < s1; i += 512) down_edge(V, TSW[i]);
        }
        __syncthreads();
    }
    if (tid < 64) {                                  // narrow deep tail: wave 0
        for (int lev = hiS; lev <= maxd; ++lev) {
            int s0 = off[lev], s1 = off[lev + 1];
            for (int i = s0 + tid; i < s1; i += 64) down_edge(V, TSW[i]);
            __threadfence_block();
        }
    }
    __syncthreads();

    for (int i = tid; i < N; i += 1024) {
        float2 v = V[i];
        out[b * N + i] = v.x / v.y;
    }
}

extern "C" void kernel_launch(void* const* d_in, const int* in_sizes, int n_in,
                              void* d_out, int out_size, void* d_ws, size_t ws_size,
                              hipStream_t stream) {
    const float* feat = (const float*)d_in[0];   // [8,1,96,96]
    const float* emb  = (const float*)d_in[1];   // [8,256,96,96]
    const int*   tree = (const int*)d_in[2];     // [8,9215,2]
    float* out = (float*)d_out;                  // [8,1,96,96]

    const size_t BN = (size_t)BS * N;
    float* distG  = (float*)d_ws;                            // BN f32 (edge-indexed sq-dist)
    int*   uparr  = (int*)((char*)d_ws + BN * 4);            // BN i32 (level order)
    int*   lvlOff = (int*)((char*)d_ws + BN * 8);            // BS*LVL_STRIDE i32

    hipMemsetAsync(distG, 0, BN * sizeof(float), stream);    // capture-legal
    setup_kernel<<<NBLK, 1024, 0, stream>>>(emb, tree, distG, uparr, lvlOff);
    dp_kernel<<<BS, 1024, 0, stream>>>(feat, lvlOff, uparr, distG, out);
}

// Round 9
// 156.710 us; speedup vs baseline: 1.0434x; 1.0434x over previous
//
#include <hip/hip_runtime.h>
#include <hip/hip_bf16.h>
#include <hip/hip_fp16.h>

#define BS 8
#define C  256
#define N  9216
#define E  9215
#define MAXD 128               // off[] bins; actual depth <= 64 (6 doubling iters)
#define LVL_STRIDE 192         // per-batch ints: [0..128]=off, 129=maxd, 130=loE, 131=hiS
#define NARROW 64              // R9: reverted to proven 64
#define NGT 31                 // weight tasks per batch: 8 tasks x 9ch + 23 x 8ch = 256
#define NBLK (BS + BS * NGT)   // 8 levels + 248 weights = 256 blocks = 256 CUs (1/CU)
                               // (R8 lesson: per-CU work is invariant at 8ch/CU; more
                               //  blocks only duplicates tree reads + atomics)

typedef __attribute__((address_space(1))) const void GVoid;
typedef __attribute__((address_space(3))) void LVoid;

// ---------------------------------------------------------------------------
// Kernel 1: identical to R5/R7 (proven; setup wall ~23 us, ~1.5x per-CU floor).
// ---------------------------------------------------------------------------
__global__ __launch_bounds__(1024) void setup_kernel(const float* __restrict__ emb,
                                                     const int* __restrict__ tree,
                                                     float* __restrict__ distG,
                                                     int* __restrict__ uparr,
                                                     int* __restrict__ lvlOff) {
    __shared__ int P[N];
    __shared__ int U[N];
    __shared__ int cnt8[MAXD * 8];
    __shared__ int tot[MAXD];
    __shared__ int sc1[MAXD];
    __shared__ int off[MAXD + 1];
    __shared__ int maxd_sh;
    const int tid = threadIdx.x;

    if (blockIdx.x >= BS) {
        // ---- weights role ----
        const int wb = blockIdx.x - BS;        // [0,248)
        const int b  = wb & 7;
        const int g  = wb >> 3;                // [0,31)
        const int c0  = (g < 8) ? g * 9 : 72 + (g - 8) * 8;
        const int cpg = (g < 8) ? 9 : 8;
        const int wave = tid >> 6, lane = tid & 63;

        float* cur = (float*)P;
        float* nxt = (float*)U;

        int se[9];
        #pragma unroll
        for (int k = 0; k < 9; ++k) {
            int e = tid + k * 1024;
            se[k] = (e < E) ? tree[((size_t)b * E + e) * 2] : 0;
        }
        float acc[9];
        #pragma unroll
        for (int k = 0; k < 9; ++k) acc[k] = 0.f;

        const float* rowbase = emb + ((size_t)b * C + c0) * N;
        for (int chk = wave; chk < 36; chk += 16)
            __builtin_amdgcn_global_load_lds(
                (GVoid*)(rowbase + chk * 256 + lane * 4),
                (LVoid*)(cur + chk * 256), 16, 0, 0);
        __syncthreads();

        for (int cc = 0; cc < cpg; ++cc) {
            if (cc + 1 < cpg) {
                const float* src = rowbase + (size_t)(cc + 1) * N;
                for (int chk = wave; chk < 36; chk += 16)
                    __builtin_amdgcn_global_load_lds(
                        (GVoid*)(src + chk * 256 + lane * 4),
                        (LVoid*)(nxt + chk * 256), 16, 0, 0);
            }
            #pragma unroll
            for (int k = 0; k < 9; ++k) {
                int e = tid + k * 1024;
                if (e < E) {
                    float d = cur[se[k]] - cur[e + 1];   // tgt = e+1 (children=arange)
                    acc[k] += d * d;
                }
            }
            __syncthreads();
            float* t = cur; cur = nxt; nxt = t;
        }
        #pragma unroll
        for (int k = 0; k < 9; ++k) {
            int e = tid + k * 1024;
            if (e < E) atomicAdd(&distG[(size_t)b * N + e], acc[k]);
        }
        return;
    }

    // ---- levels role (unchanged, proven) ----
    const int b = blockIdx.x;
    const int* tb = tree + b * E * 2;

    for (int t = tid; t < N; t += 1024)
        P[t] = (t == 0) ? 0 : (tb[(t - 1) * 2] | (1 << 16));
    for (int i = tid; i < MAXD * 8; i += 1024) cnt8[i] = 0;
    if (tid == 0) maxd_sh = 1;
    __syncthreads();

    for (int r = 0; r < 3; ++r) {
        for (int t = tid; t < N; t += 1024) {
            int p = P[t];
            int a = p & 0xffff;
            if (a == 0) U[t] = p;
            else {
                int pa = P[a];
                U[t] = (pa & 0xffff) | (((p >> 16) + (pa >> 16)) << 16);
            }
        }
        __syncthreads();
        for (int t = tid; t < N; t += 1024) {
            int p = U[t];
            int a = p & 0xffff;
            if (a == 0) P[t] = p;
            else {
                int pa = U[a];
                P[t] = (pa & 0xffff) | (((p >> 16) + (pa >> 16)) << 16);
            }
        }
        __syncthreads();
    }

    for (int t = 1 + tid; t < N; t += 1024) {
        int d = P[t] >> 16;
        atomicAdd(&cnt8[d * 8 + (tid >> 7)], 1);
    }
    __syncthreads();

    for (int d = tid; d < MAXD; d += 1024) {
        int s = 0;
        #pragma unroll
        for (int k = 0; k < 8; ++k) {
            int v = cnt8[d * 8 + k];
            cnt8[d * 8 + k] = s;
            s += v;
        }
        tot[d] = s;
        if (s > 0) atomicMax(&maxd_sh, d);
    }
    __syncthreads();

    {
        int* src = tot; int* dst = sc1;
        for (int step = 1; step < MAXD; step <<= 1) {
            for (int d = tid; d < MAXD; d += 1024)
                dst[d] = src[d] + ((d >= step) ? src[d - step] : 0);
            __syncthreads();
            int* tmp = src; src = dst; dst = tmp;
        }
        for (int d = tid; d < MAXD; d += 1024) off[d + 1] = src[d];
        if (tid == 0) off[0] = 0;
    }
    __syncthreads();

    if (tid == 0) {
        int md = maxd_sh;
        int lo = 0;
        while (lo < md && off[lo + 2] - off[lo + 1] <= NARROW) ++lo;
        int hi = md + 1;
        while (hi > lo + 1 && off[hi] - off[hi - 1] <= NARROW) --hi;
        lvlOff[b * LVL_STRIDE + 129] = md;
        lvlOff[b * LVL_STRIDE + 130] = lo;
        lvlOff[b * LVL_STRIDE + 131] = hi;
    }
    for (int t = 1 + tid; t < N; t += 1024) {
        int d = P[t] >> 16;
        int idx = atomicAdd(&cnt8[d * 8 + (tid >> 7)], 1);
        int slot = off[d] + idx;
        int p = tb[(t - 1) * 2];
        U[slot] = t | (p << 16);
    }
    __syncthreads();

    for (int i = tid; i < E; i += 1024) uparr[b * N + i] = U[i];
    for (int i = tid; i <= MAXD; i += 1024) lvlOff[b * LVL_STRIDE + i] = off[i];
}

// ---------------------------------------------------------------------------
// Kernel 2 (R9): R7's structure (1024 threads, LDS-staged init) with the
// tid<512 gate REMOVED on wide levels: barrier cost is identical (all 16
// waves must arrive) so the gate only discarded half the parallelism.
// ---------------------------------------------------------------------------
__device__ __forceinline__ void up_edge(float2* V, const int2& ew) {
    int t = ew.x & 0xffff, p = ew.x >> 16;
    float w = __int_as_float(ew.y);
    float2 vt = V[t];
    atomicAdd(&V[p].x, w * vt.x);
    atomicAdd(&V[p].y, w * vt.y);
}

__device__ __forceinline__ void down_edge(float2* V, const int2& ew) {
    int t = ew.x & 0xffff, s = ew.x >> 16;
    float w = __int_as_float(ew.y);
    float2 vs = V[s], vt = V[t];
    float c = 1.f - w * w;
    V[t] = make_float2(w * vs.x + c * vt.x, w * vs.y + c * vt.y);
}

__global__ __launch_bounds__(1024) void dp_kernel(const float* __restrict__ feat,
                                                  const int* __restrict__ lvlOff,
                                                  const int* __restrict__ uparr,
                                                  const float* __restrict__ distG,
                                                  float* __restrict__ out) {
    const int b = blockIdx.x;
    const int tid = threadIdx.x;
    __shared__ float2 V[N];           // scratch: dist stage; then (F, G)
    __shared__ int2 TSW[N];           // (child|parent<<16, w bits), level order
    __shared__ int off[MAXD + 1];
    __shared__ int meta[3];           // maxd, loE, hiS

    for (int i = tid; i <= MAXD; i += 1024) off[i] = lvlOff[b * LVL_STRIDE + i];
    if (tid < 3) meta[tid] = lvlOff[b * LVL_STRIDE + 129 + tid];

    // stage dist coalesced into V-scratch (36 KB)
    float* dScr = (float*)V;
    const float* dG = distG + b * N;
    for (int i = tid; i < N; i += 1024) dScr[i] = dG[i];
    __syncthreads();

    // TSW fill: coalesced ts + LDS gather + exp (no global dependent chain)
    const int* uA = uparr + b * N;
    for (int i = tid; i < E; i += 1024) {
        int ts = uA[i];
        float ds = dScr[(ts & 0xffff) - 1];
        TSW[i] = make_int2(ts, __float_as_int(__expf(-0.01f * ds)));
    }
    __syncthreads();

    // V init (overwrites scratch)
    for (int i = tid; i < N; i += 1024)
        V[i] = make_float2(feat[b * N + i], 1.0f);
    __syncthreads();
    const int maxd = meta[0], loE = meta[1], hiS = meta[2];

    // ---- up pass (deepest level first) ----
    if (tid < 64) {                                  // narrow deep tail: wave 0
        for (int lev = maxd; lev >= hiS; --lev) {
            int s0 = off[lev], s1 = off[lev + 1];
            for (int i = s0 + tid; i < s1; i += 64) up_edge(V, TSW[i]);
            __threadfence_block();
        }
    }
    __syncthreads();
    for (int lev = hiS - 1; lev > loE; --lev) {      // wide middle: ALL 16 waves
        int s0 = off[lev], s1 = off[lev + 1];
        for (int i = s0 + tid; i < s1; i += 1024) up_edge(V, TSW[i]);
        __syncthreads();
    }
    if (tid < 64) {                                  // narrow top: wave 0
        for (int lev = loE; lev >= 1; --lev) {
            int s0 = off[lev], s1 = off[lev + 1];
            for (int i = s0 + tid; i < s1; i += 64) up_edge(V, TSW[i]);
            __threadfence_block();
        }
    }
    __syncthreads();

    // ---- down pass (root to leaf) ----
    if (tid < 64) {                                  // narrow top: wave 0
        for (int lev = 1; lev <= loE; ++lev) {
            int s0 = off[lev], s1 = off[lev + 1];
            for (int i = s0 + tid; i < s1; i += 64) down_edge(V, TSW[i]);
            __threadfence_block();
        }
    }
    __syncthreads();
    for (int lev = loE + 1; lev < hiS; ++lev) {      // wide middle: ALL 16 waves
        int s0 = off[lev], s1 = off[lev + 1];
        for (int i = s0 + tid; i < s1; i += 1024) down_edge(V, TSW[i]);
        __syncthreads();
    }
    if (tid < 64) {                                  // narrow deep tail: wave 0
        for (int lev = hiS; lev <= maxd; ++lev) {
            int s0 = off[lev], s1 = off[lev + 1];
            for (int i = s0 + tid; i < s1; i += 64) down_edge(V, TSW[i]);
            __threadfence_block();
        }
    }
    __syncthreads();

    for (int i = tid; i < N; i += 1024) {
        float2 v = V[i];
        out[b * N + i] = v.x / v.y;
    }
}

extern "C" void kernel_launch(void* const* d_in, const int* in_sizes, int n_in,
                              void* d_out, int out_size, void* d_ws, size_t ws_size,
                              hipStream_t stream) {
    const float* feat = (const float*)d_in[0];   // [8,1,96,96]
    const float* emb  = (const float*)d_in[1];   // [8,256,96,96]
    const int*   tree = (const int*)d_in[2];     // [8,9215,2]
    float* out = (float*)d_out;                  // [8,1,96,96]

    const size_t BN = (size_t)BS * N;
    float* distG  = (float*)d_ws;                            // BN f32 (edge-indexed sq-dist)
    int*   uparr  = (int*)((char*)d_ws + BN * 4);            // BN i32 (level order)
    int*   lvlOff = (int*)((char*)d_ws + BN * 8);            // BS*LVL_STRIDE i32

    hipMemsetAsync(distG, 0, BN * sizeof(float), stream);    // capture-legal
    setup_kernel<<<NBLK, 1024, 0, stream>>>(emb, tree, distG, uparr, lvlOff);
    dp_kernel<<<BS, 1024, 0, stream>>>(feat, lvlOff, uparr, distG, out);
}